// Round 5
// baseline (801.464 us; speedup 1.0000x reference)
//
#include <hip/hip_runtime.h>
#include <hip/hip_bf16.h>

// Problem constants (match reference setup_inputs)
#define Nn 50000
#define Ee 800000
#define Gg 256
#define VOC 120
#define DH 100
#define CAPc 25
#define NTYPE 119          // types 1..119
#define DEG_R 42           // range-blocks per histogram job
#define DEG_BINS 1191      // 42*1191 = 50022 >= 50000

// ---------------- T = embed @ gcn_w : [120][100] ----------------
__global__ void t_kernel(const float* __restrict__ embed, const float* __restrict__ gcn_w,
                         float* __restrict__ T) {
    int t = blockIdx.x;
    int j = threadIdx.x;
    if (j < DH) {
        float acc = 0.f;
#pragma unroll
        for (int k = 0; k < 32; ++k) acc = fmaf(embed[t * 32 + k], gcn_w[k * DH + j], acc);
        T[t * DH + j] = acc;
    }
}

// ---------------- selection: first 25 nodes per (type, side), 1 wave/block ----
// selpos[node] = (t-1)*25 + rank for the first 25 nodes of type t, else -1 (pre-memset).
__global__ __launch_bounds__(64) void sel_kernel(const int* __restrict__ feat_src,
                                                 const int* __restrict__ feat_tar,
                                                 int* __restrict__ selpos_src,
                                                 int* __restrict__ selpos_tar,
                                                 int* __restrict__ fullcnt) {
    int t = blockIdx.x + 1;
    int side = blockIdx.y;
    const int* f = side ? feat_tar : feat_src;
    int* selpos = side ? selpos_tar : selpos_src;
    int lane = threadIdx.x;
    int tot = 0;
    for (int chunk = 0; chunk < 782; ++chunk) {  // 782*64 = 50048 >= 50000
        int i = chunk * 64 + lane;
        int v = (i < Nn) ? f[i] : -1;
        bool match = (v == t);
        unsigned long long m = __ballot(match);
        if (match) {
            int rank = tot + __popcll(m & ((1ull << lane) - 1ull));
            if (rank < CAPc) selpos[i] = (t - 1) * CAPc + rank;
        }
        tot += __popcll(m);
    }
    if (lane == 0) fullcnt[side * VOC + t] = tot;
}

// ---------------- degree histograms WITHOUT global atomics ----------------
// job = blockIdx.y: (graph g = job>>1, isdst = job&1). Each block owns an exclusive
// node range, scans the full endpoint array, counts in LDS, plain-stores results.
// src jobs emit pc[n] = {mask*rsqrt(outdeg), feat-bits}; dst jobs emit rs[n]=rsqrt(indeg).
__global__ __launch_bounds__(256) void degrange_kernel(
        const int* __restrict__ ei0, const int* __restrict__ ei1, const int* __restrict__ ei2,
        const int* __restrict__ feat0, const int* __restrict__ feat1, const int* __restrict__ feat2,
        const float* __restrict__ mask, float2* __restrict__ pc, float* __restrict__ rs) {
    int job = blockIdx.y, g = job >> 1, isdst = job & 1;
    const int* ei = (g == 0) ? ei0 : (g == 1) ? ei1 : ei2;
    const uint4* a4 = (const uint4*)(ei + (isdst ? Ee : 0));
    unsigned base = blockIdx.x * DEG_BINS;
    __shared__ int hist[DEG_BINS];
    int tid = threadIdx.x;
    for (int i = tid; i < DEG_BINS; i += 256) hist[i] = 0;
    __syncthreads();
    for (int idx = tid; idx < Ee / 4; idx += 256) {
        uint4 v = a4[idx];
        unsigned q;
        q = v.x - base; if (q < DEG_BINS) atomicAdd(&hist[q], 1);
        q = v.y - base; if (q < DEG_BINS) atomicAdd(&hist[q], 1);
        q = v.z - base; if (q < DEG_BINS) atomicAdd(&hist[q], 1);
        q = v.w - base; if (q < DEG_BINS) atomicAdd(&hist[q], 1);
    }
    __syncthreads();
    if (!isdst) {
        const int* ft = (g == 0) ? feat0 : (g == 1) ? feat1 : feat2;
        float2* pcg = pc + (size_t)g * Nn;
        bool hasmask = (g == 0);
        for (int i = tid; i < DEG_BINS; i += 256) {
            int n = base + i;
            if (n < Nn) {
                float cf = rsqrtf((float)max(hist[i], 1));
                if (hasmask) cf *= mask[n];
                pcg[n] = make_float2(cf, __int_as_float(ft[n]));
            }
        }
    } else {
        float* rsg = rs + (size_t)g * Nn;
        for (int i = tid; i < DEG_BINS; i += 256) {
            int n = base + i;
            if (n < Nn) rsg[n] = rsqrtf((float)max(hist[i], 1));
        }
    }
}

// ---------------- W[dst][type] += coef[src]  (single atomic per edge) ----------------
__global__ __launch_bounds__(256) void wacc_kernel(const int* __restrict__ ei,
                                                   const float2* __restrict__ pc,
                                                   float* __restrict__ W) {
    int e = blockIdx.x * 256 + threadIdx.x;
    if (e < Ee) {
        int s = ei[e], d = ei[Ee + e];
        float2 p = pc[s];
        atomicAdd(&W[(size_t)d * VOC + __float_as_int(p.y)], p.x);
    }
}

// ---------------- h = relu((W@T)*rs + b); fused pool-max; scatter selected rows ------
// 256 threads, 64 rows/block, 8 rows x 4 cols per thread.
// LDS: T (48000B) + W tile (30720B) + pool locals + selpos slice ~ 79.8 KB -> 2 blocks/CU.
__global__ __launch_bounds__(256, 2) void h_kernel(const float* __restrict__ W,
                                                   const float* __restrict__ T,
                                                   const float* __restrict__ rs,
                                                   const int* __restrict__ selpos,
                                                   float* __restrict__ h_sel,
                                                   const float* __restrict__ gcn_b,
                                                   float* __restrict__ pool) {
    __shared__ float smem[12000 + 64 * 120];
    __shared__ float pl[2 * DH];
    __shared__ int sp_l[64];
    float* Tl = smem;
    float* Wt = smem + 12000;
    int tid = threadIdx.x;
    int r0 = blockIdx.x * 64;

    float4* Tl4 = (float4*)Tl;
    const float4* Tg4 = (const float4*)T;
#pragma unroll
    for (int i = 0; i < 12; ++i) {
        int idx = tid + i * 256;
        if (idx < 3000) Tl4[idx] = Tg4[idx];
    }
    float4* Wt4 = (float4*)Wt;
    const float4* Wg4 = (const float4*)(W + (size_t)r0 * VOC);
#pragma unroll
    for (int i = 0; i < 8; ++i) {
        int idx = tid + i * 256;
        if (idx < 1920) Wt4[idx] = Wg4[idx];  // last block over-reads into ws (harmless)
    }
    if (tid < 2 * DH) pl[tid] = 0.f;
    if (tid < 64) {
        int row = r0 + tid;
        sp_l[tid] = (selpos != nullptr && row < Nn) ? selpos[row] : -1;
    }
    __syncthreads();

    int tc = tid & 31, tr = tid >> 5;
    int c0 = tc * 4;
    float4 acc[8];
#pragma unroll
    for (int u = 0; u < 8; ++u) acc[u] = make_float4(0.f, 0.f, 0.f, 0.f);

#pragma unroll 2
    for (int tq = 0; tq < 30; ++tq) {
        const float* tb = &Tl[tq * 4 * DH + c0];
        float4 tv0 = *(const float4*)(tb);
        float4 tv1 = *(const float4*)(tb + DH);
        float4 tv2 = *(const float4*)(tb + 2 * DH);
        float4 tv3 = *(const float4*)(tb + 3 * DH);
#pragma unroll
        for (int u = 0; u < 8; ++u) {
            float4 wv = *(const float4*)&Wt[(tr * 8 + u) * VOC + tq * 4];
            acc[u].x = fmaf(wv.x, tv0.x, fmaf(wv.y, tv1.x, fmaf(wv.z, tv2.x, fmaf(wv.w, tv3.x, acc[u].x))));
            acc[u].y = fmaf(wv.x, tv0.y, fmaf(wv.y, tv1.y, fmaf(wv.z, tv2.y, fmaf(wv.w, tv3.y, acc[u].y))));
            acc[u].z = fmaf(wv.x, tv0.z, fmaf(wv.y, tv1.z, fmaf(wv.z, tv2.z, fmaf(wv.w, tv3.z, acc[u].z))));
            acc[u].w = fmaf(wv.x, tv0.w, fmaf(wv.y, tv1.w, fmaf(wv.z, tv2.w, fmaf(wv.w, tv3.w, acc[u].w))));
        }
    }

    int gb0 = (r0 * Gg) / Nn;
    if (tc < 25) {
        float4 bias = *(const float4*)&gcn_b[c0];
        float4 pm = make_float4(0.f, 0.f, 0.f, 0.f);
        int curgl = 0;
#pragma unroll
        for (int u = 0; u < 8; ++u) {
            int row = r0 + tr * 8 + u;
            if (row < Nn) {
                float sc = rs[row];
                float4 v;
                v.x = fmaxf(fmaf(acc[u].x, sc, bias.x), 0.f);
                v.y = fmaxf(fmaf(acc[u].y, sc, bias.y), 0.f);
                v.z = fmaxf(fmaf(acc[u].z, sc, bias.z), 0.f);
                v.w = fmaxf(fmaf(acc[u].w, sc, bias.w), 0.f);
                int sp = sp_l[tr * 8 + u];
                if (sp >= 0) *(float4*)&h_sel[(size_t)sp * DH + c0] = v;
                int gl = (row * Gg) / Nn - gb0;
                if (gl != curgl) {  // rows are consecutive -> at most one switch
                    atomicMax((int*)&pl[curgl * DH + c0 + 0], __float_as_int(pm.x));
                    atomicMax((int*)&pl[curgl * DH + c0 + 1], __float_as_int(pm.y));
                    atomicMax((int*)&pl[curgl * DH + c0 + 2], __float_as_int(pm.z));
                    atomicMax((int*)&pl[curgl * DH + c0 + 3], __float_as_int(pm.w));
                    pm = v;
                    curgl = gl;
                } else {
                    pm.x = fmaxf(pm.x, v.x);
                    pm.y = fmaxf(pm.y, v.y);
                    pm.z = fmaxf(pm.z, v.z);
                    pm.w = fmaxf(pm.w, v.w);
                }
            }
        }
        atomicMax((int*)&pl[curgl * DH + c0 + 0], __float_as_int(pm.x));
        atomicMax((int*)&pl[curgl * DH + c0 + 1], __float_as_int(pm.y));
        atomicMax((int*)&pl[curgl * DH + c0 + 2], __float_as_int(pm.z));
        atomicMax((int*)&pl[curgl * DH + c0 + 3], __float_as_int(pm.w));
    }
    __syncthreads();
    int lastrow = min(r0 + 63, Nn - 1);
    int ng = (lastrow * Gg) / Nn - gb0 + 1;
    if (tid < DH * ng) {
        int gl = tid / DH, c = tid % DH;
        atomicMax((int*)&pool[(gb0 + gl) * DH + c], __float_as_int(pl[gl * DH + c]));
    }
}

// ---------------- pooled GEMMs + defect prob ----------------
__global__ void poolgemm_kernel(const float* __restrict__ pool, const float* __restrict__ fc_w,
                                const float* __restrict__ fc_b, const float* __restrict__ def_w,
                                const float* __restrict__ def_b, float* __restrict__ out) {
    int g = blockIdx.x;
    __shared__ float xb[32];
    int tid = threadIdx.x;  // 128
    if (tid < 96) {
        int p = tid >> 5, j = tid & 31;
        float acc = fc_b[j];
        const float* pr = pool + p * (Gg * DH) + g * DH;
#pragma unroll 4
        for (int k = 0; k < DH; ++k) acc = fmaf(pr[k], fc_w[k * 32 + j], acc);
        int off = (p == 0) ? 0 : (p == 1 ? 8448 : 16640);
        out[off + g * 32 + j] = acc;
        if (p == 0) xb[j] = acc;
    }
    __syncthreads();
    if (tid < 32) {
        float v = xb[tid] * def_w[tid];
        for (int o = 16; o; o >>= 1) v += __shfl_down(v, o, 64);
        if (tid == 0) out[8192 + g] = 1.f / (1.f + expf(-(v + def_b[0])));
    }
}

// ---------------- X features for selected rows: X[type][50][32] ----------------
__global__ __launch_bounds__(256) void xfeat_kernel(const float* __restrict__ h_sel,
                                                    const int* __restrict__ fullcnt,
                                                    const float* __restrict__ fc_w,
                                                    const float* __restrict__ fc_b,
                                                    float* __restrict__ X) {
    int t = blockIdx.x;  // type t+1
    __shared__ float fw[DH * 32];
    for (int i = threadIdx.x; i < DH * 32; i += 256) fw[i] = fc_w[i];
    __syncthreads();
    int cs = min(fullcnt[t + 1], CAPc);
    int ct = min(fullcnt[VOC + t + 1], CAPc);
    int j = threadIdx.x & 31, rg = threadIdx.x >> 5;
    for (int r = rg; r < 2 * CAPc; r += 8) {
        int side = r / CAPc, rr = r % CAPc;
        int cnt = side ? ct : cs;
        float acc = 0.f;
        if (rr < cnt) {
            const float* hr = h_sel + ((size_t)side * NTYPE * CAPc + (size_t)t * CAPc + rr) * DH;
            acc = fc_b[j];
#pragma unroll 4
            for (int k = 0; k < DH; ++k) acc = fmaf(hr[k], fw[k * 32 + j], acc);
        }
        X[(size_t)t * 1600 + r * 32 + j] = acc;
    }
}

// ---------------- per-type MMD ----------------
__device__ __forceinline__ float block_reduce256(float v, float* red, int tid) {
    __syncthreads();
    red[tid] = v;
    __syncthreads();
    for (int s = 128; s > 0; s >>= 1) {
        if (tid < s) red[tid] += red[tid + s];
        __syncthreads();
    }
    return red[0];
}

__global__ __launch_bounds__(256) void mmd_kernel(const float* __restrict__ X,
                                                  const int* __restrict__ fullcnt,
                                                  float* __restrict__ losses) {
    int t = blockIdx.x;  // type t+1
    __shared__ float Xs[50 * 32];
    __shared__ float D2[50 * 50];
    __shared__ float red[256];
    int tid = threadIdx.x;
    for (int i = tid; i < 1600; i += 256) Xs[i] = X[(size_t)t * 1600 + i];
    __syncthreads();
    int scF = fullcnt[t + 1];
    int tcF = fullcnt[VOC + t + 1];
    int m = min(scF, CAPc), n2 = min(tcF, CAPc);
    float bwpart = 0.f;
    for (int idx = tid; idx < 2500; idx += 256) {
        int i = idx / 50, j = idx % 50;
        float d = 0.f;
#pragma unroll
        for (int k = 0; k < 32; ++k) {
            float df = Xs[i * 32 + k] - Xs[j * 32 + k];
            d = fmaf(df, df, d);
        }
        D2[idx] = d;
        bool vi = (i < CAPc) ? (i < m) : (i - CAPc < n2);
        bool vj = (j < CAPc) ? (j < m) : (j - CAPc < n2);
        if (vi && vj) bwpart += d;
    }
    float bwsum = block_reduce256(bwpart, red, tid);
    float ntot = (float)(m + n2);
    float bw = bwsum / fmaxf(ntot * ntot - ntot, 1.f) * 0.25f;  // / KER_MUL^(KER_NUM//2)
    float bws[5];
#pragma unroll
    for (int k = 0; k < 5; ++k) bws[k] = fmaxf(bw * (float)(1 << k), 1e-8f);
    float xx = 0.f, yy = 0.f, xy = 0.f;
    for (int idx = tid; idx < 2500; idx += 256) {
        int i = idx / 50, j = idx % 50;
        bool vi = (i < CAPc) ? (i < m) : (i - CAPc < n2);
        bool vj = (j < CAPc) ? (j < m) : (j - CAPc < n2);
        if (!(vi && vj)) continue;
        float d = D2[idx];
        float kv = 0.f;
#pragma unroll
        for (int k = 0; k < 5; ++k) kv += expf(-d / bws[k]);
        if (i < CAPc && j < CAPc) xx += kv;
        else if (i >= CAPc && j >= CAPc) yy += kv;
        else if (i < CAPc) xy += kv;
    }
    float rxx = block_reduce256(xx, red, tid);
    float ryy = block_reduce256(yy, red, tid);
    float rxy = block_reduce256(xy, red, tid);
    if (tid == 0) {
        float fm = (float)m, fn = (float)n2;
        float XX = rxx / fmaxf(fm * fm, 1.f);
        float YY = ryy / fmaxf(fn * fn, 1.f);
        float XY = rxy / fmaxf(fm * fn, 1.f);
        float loss = XX + YY - 2.f * XY;
        int inc = (scF >= 5 && tcF >= 5) ? 1 : 0;
        losses[t * 2 + 0] = inc ? loss : 0.f;
        losses[t * 2 + 1] = (float)inc;
    }
}

__global__ void final_kernel(const float* __restrict__ losses, float* __restrict__ out) {
    __shared__ float red[128], redc[128];
    int tid = threadIdx.x;
    float s = 0.f, c = 0.f;
    for (int t = tid; t < NTYPE; t += 128) {
        s += losses[t * 2];
        c += losses[t * 2 + 1];
    }
    red[tid] = s;
    redc[tid] = c;
    __syncthreads();
    for (int st = 64; st > 0; st >>= 1) {
        if (tid < st) {
            red[tid] += red[tid + st];
            redc[tid] += redc[tid + st];
        }
        __syncthreads();
    }
    if (tid == 0) out[24832] = redc[0] > 0.f ? red[0] / fmaxf(redc[0], 1.f) : 0.f;
}

extern "C" void kernel_launch(void* const* d_in, const int* in_sizes, int n_in,
                              void* d_out, int out_size, void* d_ws, size_t ws_size,
                              hipStream_t stream) {
    const int* feat = (const int*)d_in[0];
    const int* feat_src = (const int*)d_in[1];
    const int* feat_tar = (const int*)d_in[2];
    const int* ei0 = (const int*)d_in[3];
    const int* ei1 = (const int*)d_in[4];
    const int* ei2 = (const int*)d_in[5];
    const float* mask = (const float*)d_in[7];
    const float* embed = (const float*)d_in[8];
    const float* gcn_w = (const float*)d_in[9];
    const float* gcn_b = (const float*)d_in[10];
    const float* fc_w = (const float*)d_in[11];
    const float* fc_b = (const float*)d_in[12];
    const float* def_w = (const float*)d_in[13];
    const float* def_b = (const float*)d_in[14];
    float* out = (float*)d_out;

    char* wsb = (char*)d_ws;
    float* W = (float*)(wsb + 0);               // 24,000,000
    float* T = (float*)(wsb + 24000000);        // 48,000
    float* pool = (float*)(wsb + 24048000);     // 307,200
    float2* pc = (float2*)(wsb + 24355200);     // 1,200,000 (3 x 50000 x 8B)
    float* rs = (float*)(wsb + 25555200);       // 600,000   (3 x 50000 x 4B)
    int* selpos = (int*)(wsb + 26155200);       // 400,000   (src then tar)
    float* h_sel = (float*)(wsb + 26555200);    // 2,380,000 (2 x 119 x 25 x 100 f32)
    int* fullcnt = (int*)(wsb + 28935200);      // 960
    float* X = (float*)(wsb + 28936160);        // 761,600
    float* losses = (float*)(wsb + 29697760);   // 952   -> total ~29.7 MB

    const int* eis[3] = {ei0, ei1, ei2};

    hipMemsetAsync(pool, 0, 3 * Gg * DH * sizeof(float), stream);
    hipMemsetAsync(selpos, 0xFF, 2 * Nn * sizeof(int), stream);  // -1

    t_kernel<<<VOC, 128, 0, stream>>>(embed, gcn_w, T);
    sel_kernel<<<dim3(NTYPE, 2), 64, 0, stream>>>(feat_src, feat_tar, selpos, selpos + Nn, fullcnt);
    degrange_kernel<<<dim3(DEG_R, 6), 256, 0, stream>>>(ei0, ei1, ei2, feat, feat_src, feat_tar,
                                                        mask, pc, rs);

    for (int p = 0; p < 3; ++p) {
        hipMemsetAsync(W, 0, (size_t)Nn * VOC * sizeof(float), stream);
        wacc_kernel<<<(Ee + 255) / 256, 256, 0, stream>>>(eis[p], pc + (size_t)p * Nn, W);
        const int* sp = (p == 0) ? nullptr : (p == 1 ? selpos : selpos + Nn);
        float* hs = h_sel + (size_t)(p == 2 ? NTYPE * CAPc * DH : 0);
        h_kernel<<<(Nn + 63) / 64, 256, 0, stream>>>(W, T, rs + (size_t)p * Nn, sp, hs, gcn_b,
                                                     pool + p * (Gg * DH));
    }

    poolgemm_kernel<<<Gg, 128, 0, stream>>>(pool, fc_w, fc_b, def_w, def_b, out);
    xfeat_kernel<<<NTYPE, 256, 0, stream>>>(h_sel, fullcnt, fc_w, fc_b, X);
    mmd_kernel<<<NTYPE, 256, 0, stream>>>(X, fullcnt, losses);
    final_kernel<<<1, 128, 0, stream>>>(losses, out);
}

// Round 6
// 371.372 us; speedup vs baseline: 2.1581x; 2.1581x over previous
//
#include <hip/hip_runtime.h>
#include <hip/hip_bf16.h>

// Problem constants (match reference setup_inputs)
#define Nn 50000
#define Ee 800000
#define Gg 256
#define VOC 120
#define DH 100
#define CAPc 25
#define NTYPE 119          // types 1..119
#define NCHUNK 196         // ceil(50000/256)
#define DR 4               // node ranges (12500 nodes each)
#define DS 32              // edge slices (25000 edges each)
#define DWORDS 6250        // 12500 nodes / 2 per 32-bit word (16-bit packed counts)

// ---------------- T = embed @ gcn_w : [120][100] ----------------
__global__ void t_kernel(const float* __restrict__ embed, const float* __restrict__ gcn_w,
                         float* __restrict__ T) {
    int t = blockIdx.x;
    int j = threadIdx.x;
    if (j < DH) {
        float acc = 0.f;
#pragma unroll
        for (int k = 0; k < 32; ++k) acc = fmaf(embed[t * 32 + k], gcn_w[k * DH + j], acc);
        T[t * DH + j] = acc;
    }
}

// ---------------- selection: first 25 nodes per (type, side) ----------------
__global__ void selcount_kernel(const int* __restrict__ feat_src, const int* __restrict__ feat_tar,
                                int* __restrict__ chunkcnt) {
    int chunk = blockIdx.x, side = blockIdx.y;
    const int* f = side ? feat_tar : feat_src;
    __shared__ int hist[VOC];
    int tid = threadIdx.x;
    if (tid < VOC) hist[tid] = 0;
    __syncthreads();
    int i = chunk * 256 + tid;
    if (i < Nn) atomicAdd(&hist[f[i]], 1);
    __syncthreads();
    if (tid < VOC) chunkcnt[(side * NCHUNK + chunk) * VOC + tid] = hist[tid];
}

__global__ void selprefix_kernel(const int* __restrict__ chunkcnt, int* __restrict__ base,
                                 int* __restrict__ fullcnt) {
    int tid = threadIdx.x;  // 256
    if (tid < 2 * VOC) {
        int side = tid / VOC, t = tid % VOC;
        int run = 0;
        for (int c = 0; c < NCHUNK; ++c) {
            base[(side * NCHUNK + c) * VOC + t] = run;
            run += chunkcnt[(side * NCHUNK + c) * VOC + t];
        }
        fullcnt[side * VOC + t] = run;
    }
}

// writes selpos[node] = (t-1)*25 + rank for the first 25 nodes of each type (else stays -1)
__global__ void selgather_kernel(const int* __restrict__ feat_src, const int* __restrict__ feat_tar,
                                 const int* __restrict__ base, int* __restrict__ selpos_src,
                                 int* __restrict__ selpos_tar) {
    int chunk = blockIdx.x, side = blockIdx.y;
    const int* f = side ? feat_tar : feat_src;
    int* selpos = side ? selpos_tar : selpos_src;
    __shared__ int types[256];
    int tid = threadIdx.x;
    int i = chunk * 256 + tid;
    int t = (i < Nn) ? f[i] : -1;
    types[tid] = t;
    int bv = 0;
    bool need = (t >= 1);
    if (need) {
        bv = base[(side * NCHUNK + chunk) * VOC + t];
        need = (bv < CAPc);
    }
    int any = __syncthreads_count((int)need);  // also the barrier making types[] visible
    if (any == 0) return;                      // ~97% of blocks exit here
    if (need) {
        int rank = bv;
        for (int q = 0; q < 256; ++q)
            if (q < tid && types[q] == t) rank++;
        if (rank < CAPc) selpos[i] = (t - 1) * CAPc + rank;
    }
}

// ---------------- degree histograms: 2-level, atomic-free in global ----------------
// Grid: x = r + DR*s (range, slice), y = job (graph g = job>>1, isdst = job&1).
// Each block scans its 25000-edge slice, counts its 12500-node range in LDS with
// 16-bit packed counters (2 nodes/word), plain-stores a 6250-word partial.
__global__ __launch_bounds__(256) void deghist_kernel(
        const int* __restrict__ ei0, const int* __restrict__ ei1, const int* __restrict__ ei2,
        int* __restrict__ partial) {
    int job = blockIdx.y, g = job >> 1, isdst = job & 1;
    int r = blockIdx.x & (DR - 1), s = blockIdx.x >> 2;
    const int* ei = (g == 0) ? ei0 : (g == 1) ? ei1 : ei2;
    const uint4* a4 = (const uint4*)(ei + (isdst ? Ee : 0) + s * (Ee / DS));
    __shared__ int hist[DWORDS];
    int tid = threadIdx.x;
    for (int i = tid; i < DWORDS; i += 256) hist[i] = 0;
    __syncthreads();
    unsigned base = r * (2 * DWORDS);
    for (int idx = tid; idx < (Ee / DS) / 4; idx += 256) {  // ~24 iters
        uint4 v = a4[idx];
        unsigned q;
        q = v.x - base; if (q < 2 * DWORDS) atomicAdd(&hist[q >> 1], 1 << ((q & 1) * 16));
        q = v.y - base; if (q < 2 * DWORDS) atomicAdd(&hist[q >> 1], 1 << ((q & 1) * 16));
        q = v.z - base; if (q < 2 * DWORDS) atomicAdd(&hist[q >> 1], 1 << ((q & 1) * 16));
        q = v.w - base; if (q < 2 * DWORDS) atomicAdd(&hist[q >> 1], 1 << ((q & 1) * 16));
    }
    __syncthreads();
    int* outp = partial + ((size_t)(job * DR + r) * DS + s) * DWORDS;
    for (int i = tid; i < DWORDS; i += 256) outp[i] = hist[i];
}

// merge 32 packed partials per word; emit pc (src jobs) / rs (dst jobs).
__global__ __launch_bounds__(256) void degmerge_kernel(
        const int* __restrict__ partial,
        const int* __restrict__ feat0, const int* __restrict__ feat1, const int* __restrict__ feat2,
        const float* __restrict__ mask, float2* __restrict__ pc, float* __restrict__ rs) {
    int idx = blockIdx.x * 256 + threadIdx.x;
    if (idx >= 6 * DR * DWORDS) return;
    int job = idx / (DR * DWORDS);
    int rem = idx - job * (DR * DWORDS);
    int r = rem / DWORDS, w = rem - r * DWORDS;
    int g = job >> 1, isdst = job & 1;
    const int* p = partial + ((size_t)(job * DR + r) * DS) * DWORDS + w;
    int sum = 0;
#pragma unroll 8
    for (int s = 0; s < DS; ++s) sum += p[s * DWORDS];  // packed 16-bit fields, no overflow
    int c0 = sum & 0xFFFF, c1 = sum >> 16;
    int n0 = r * (2 * DWORDS) + 2 * w;
    if (isdst) {
        float2 v = make_float2(rsqrtf((float)max(c0, 1)), rsqrtf((float)max(c1, 1)));
        ((float2*)(rs + (size_t)g * Nn))[r * DWORDS + w] = v;
    } else {
        const int* ft = (g == 0) ? feat0 : (g == 1) ? feat1 : feat2;
        float cf0 = rsqrtf((float)max(c0, 1));
        float cf1 = rsqrtf((float)max(c1, 1));
        if (g == 0) {
            cf0 *= mask[n0];
            cf1 *= mask[n0 + 1];
        }
        float4 v = make_float4(cf0, __int_as_float(ft[n0]), cf1, __int_as_float(ft[n0 + 1]));
        ((float4*)(pc + (size_t)g * Nn))[r * DWORDS + w] = v;
    }
}

// ---------------- W[dst][type] += coef[src]  (single atomic per edge) ----------------
__global__ __launch_bounds__(256) void wacc_kernel(const int* __restrict__ ei,
                                                   const float2* __restrict__ pc,
                                                   float* __restrict__ W) {
    int e = blockIdx.x * 256 + threadIdx.x;
    if (e < Ee) {
        int s = ei[e], d = ei[Ee + e];
        float2 p = pc[s];
        atomicAdd(&W[(size_t)d * VOC + __float_as_int(p.y)], p.x);
    }
}

// ---------------- h = relu((W@T)*rs + b); fused pool-max; scatter selected rows ------
// 256 threads, 64 rows/block, 8 rows x 4 cols per thread.
__global__ __launch_bounds__(256, 2) void h_kernel(const float* __restrict__ W,
                                                   const float* __restrict__ T,
                                                   const float* __restrict__ rs,
                                                   const int* __restrict__ selpos,
                                                   float* __restrict__ h_sel,
                                                   const float* __restrict__ gcn_b,
                                                   float* __restrict__ pool) {
    __shared__ float smem[12000 + 64 * 120];
    __shared__ float pl[2 * DH];
    __shared__ int sp_l[64];
    float* Tl = smem;
    float* Wt = smem + 12000;
    int tid = threadIdx.x;
    int r0 = blockIdx.x * 64;

    float4* Tl4 = (float4*)Tl;
    const float4* Tg4 = (const float4*)T;
#pragma unroll
    for (int i = 0; i < 12; ++i) {
        int idx = tid + i * 256;
        if (idx < 3000) Tl4[idx] = Tg4[idx];
    }
    float4* Wt4 = (float4*)Wt;
    const float4* Wg4 = (const float4*)(W + (size_t)r0 * VOC);
#pragma unroll
    for (int i = 0; i < 8; ++i) {
        int idx = tid + i * 256;
        if (idx < 1920) Wt4[idx] = Wg4[idx];  // last block over-reads into ws (harmless)
    }
    if (tid < 2 * DH) pl[tid] = 0.f;
    if (tid < 64) {
        int row = r0 + tid;
        sp_l[tid] = (selpos != nullptr && row < Nn) ? selpos[row] : -1;
    }
    __syncthreads();

    int tc = tid & 31, tr = tid >> 5;
    int c0 = tc * 4;
    float4 acc[8];
#pragma unroll
    for (int u = 0; u < 8; ++u) acc[u] = make_float4(0.f, 0.f, 0.f, 0.f);

#pragma unroll 2
    for (int tq = 0; tq < 30; ++tq) {
        const float* tb = &Tl[tq * 4 * DH + c0];
        float4 tv0 = *(const float4*)(tb);
        float4 tv1 = *(const float4*)(tb + DH);
        float4 tv2 = *(const float4*)(tb + 2 * DH);
        float4 tv3 = *(const float4*)(tb + 3 * DH);
#pragma unroll
        for (int u = 0; u < 8; ++u) {
            float4 wv = *(const float4*)&Wt[(tr * 8 + u) * VOC + tq * 4];
            acc[u].x = fmaf(wv.x, tv0.x, fmaf(wv.y, tv1.x, fmaf(wv.z, tv2.x, fmaf(wv.w, tv3.x, acc[u].x))));
            acc[u].y = fmaf(wv.x, tv0.y, fmaf(wv.y, tv1.y, fmaf(wv.z, tv2.y, fmaf(wv.w, tv3.y, acc[u].y))));
            acc[u].z = fmaf(wv.x, tv0.z, fmaf(wv.y, tv1.z, fmaf(wv.z, tv2.z, fmaf(wv.w, tv3.z, acc[u].z))));
            acc[u].w = fmaf(wv.x, tv0.w, fmaf(wv.y, tv1.w, fmaf(wv.z, tv2.w, fmaf(wv.w, tv3.w, acc[u].w))));
        }
    }

    int gb0 = (r0 * Gg) / Nn;
    if (tc < 25) {
        float4 bias = *(const float4*)&gcn_b[c0];
        float4 pm = make_float4(0.f, 0.f, 0.f, 0.f);
        int curgl = 0;
#pragma unroll
        for (int u = 0; u < 8; ++u) {
            int row = r0 + tr * 8 + u;
            if (row < Nn) {
                float sc = rs[row];
                float4 v;
                v.x = fmaxf(fmaf(acc[u].x, sc, bias.x), 0.f);
                v.y = fmaxf(fmaf(acc[u].y, sc, bias.y), 0.f);
                v.z = fmaxf(fmaf(acc[u].z, sc, bias.z), 0.f);
                v.w = fmaxf(fmaf(acc[u].w, sc, bias.w), 0.f);
                int sp = sp_l[tr * 8 + u];
                if (sp >= 0) *(float4*)&h_sel[(size_t)sp * DH + c0] = v;
                int gl = (row * Gg) / Nn - gb0;
                if (gl != curgl) {  // rows are consecutive -> at most one switch
                    atomicMax((int*)&pl[curgl * DH + c0 + 0], __float_as_int(pm.x));
                    atomicMax((int*)&pl[curgl * DH + c0 + 1], __float_as_int(pm.y));
                    atomicMax((int*)&pl[curgl * DH + c0 + 2], __float_as_int(pm.z));
                    atomicMax((int*)&pl[curgl * DH + c0 + 3], __float_as_int(pm.w));
                    pm = v;
                    curgl = gl;
                } else {
                    pm.x = fmaxf(pm.x, v.x);
                    pm.y = fmaxf(pm.y, v.y);
                    pm.z = fmaxf(pm.z, v.z);
                    pm.w = fmaxf(pm.w, v.w);
                }
            }
        }
        atomicMax((int*)&pl[curgl * DH + c0 + 0], __float_as_int(pm.x));
        atomicMax((int*)&pl[curgl * DH + c0 + 1], __float_as_int(pm.y));
        atomicMax((int*)&pl[curgl * DH + c0 + 2], __float_as_int(pm.z));
        atomicMax((int*)&pl[curgl * DH + c0 + 3], __float_as_int(pm.w));
    }
    __syncthreads();
    int lastrow = min(r0 + 63, Nn - 1);
    int ng = (lastrow * Gg) / Nn - gb0 + 1;
    if (tid < DH * ng) {
        int gl = tid / DH, c = tid % DH;
        atomicMax((int*)&pool[(gb0 + gl) * DH + c], __float_as_int(pl[gl * DH + c]));
    }
}

// ---------------- pooled GEMMs + defect prob ----------------
__global__ void poolgemm_kernel(const float* __restrict__ pool, const float* __restrict__ fc_w,
                                const float* __restrict__ fc_b, const float* __restrict__ def_w,
                                const float* __restrict__ def_b, float* __restrict__ out) {
    int g = blockIdx.x;
    __shared__ float xb[32];
    int tid = threadIdx.x;  // 128
    if (tid < 96) {
        int p = tid >> 5, j = tid & 31;
        float acc = fc_b[j];
        const float* pr = pool + p * (Gg * DH) + g * DH;
#pragma unroll 4
        for (int k = 0; k < DH; ++k) acc = fmaf(pr[k], fc_w[k * 32 + j], acc);
        int off = (p == 0) ? 0 : (p == 1 ? 8448 : 16640);
        out[off + g * 32 + j] = acc;
        if (p == 0) xb[j] = acc;
    }
    __syncthreads();
    if (tid < 32) {
        float v = xb[tid] * def_w[tid];
        for (int o = 16; o; o >>= 1) v += __shfl_down(v, o, 64);
        if (tid == 0) out[8192 + g] = 1.f / (1.f + expf(-(v + def_b[0])));
    }
}

// ---------------- X features for selected rows: X[type][50][32] ----------------
__global__ __launch_bounds__(256) void xfeat_kernel(const float* __restrict__ h_sel,
                                                    const int* __restrict__ fullcnt,
                                                    const float* __restrict__ fc_w,
                                                    const float* __restrict__ fc_b,
                                                    float* __restrict__ X) {
    int t = blockIdx.x;  // type t+1
    __shared__ float fw[DH * 32];
    for (int i = threadIdx.x; i < DH * 32; i += 256) fw[i] = fc_w[i];
    __syncthreads();
    int cs = min(fullcnt[t + 1], CAPc);
    int ct = min(fullcnt[VOC + t + 1], CAPc);
    int j = threadIdx.x & 31, rg = threadIdx.x >> 5;
    for (int r = rg; r < 2 * CAPc; r += 8) {
        int side = r / CAPc, rr = r % CAPc;
        int cnt = side ? ct : cs;
        float acc = 0.f;
        if (rr < cnt) {
            const float* hr = h_sel + ((size_t)side * NTYPE * CAPc + (size_t)t * CAPc + rr) * DH;
            acc = fc_b[j];
#pragma unroll 4
            for (int k = 0; k < DH; ++k) acc = fmaf(hr[k], fw[k * 32 + j], acc);
        }
        X[(size_t)t * 1600 + r * 32 + j] = acc;
    }
}

// ---------------- per-type MMD ----------------
__device__ __forceinline__ float block_reduce256(float v, float* red, int tid) {
    __syncthreads();
    red[tid] = v;
    __syncthreads();
    for (int s = 128; s > 0; s >>= 1) {
        if (tid < s) red[tid] += red[tid + s];
        __syncthreads();
    }
    return red[0];
}

__global__ __launch_bounds__(256) void mmd_kernel(const float* __restrict__ X,
                                                  const int* __restrict__ fullcnt,
                                                  float* __restrict__ losses) {
    int t = blockIdx.x;  // type t+1
    __shared__ float Xs[50 * 32];
    __shared__ float D2[50 * 50];
    __shared__ float red[256];
    int tid = threadIdx.x;
    for (int i = tid; i < 1600; i += 256) Xs[i] = X[(size_t)t * 1600 + i];
    __syncthreads();
    int scF = fullcnt[t + 1];
    int tcF = fullcnt[VOC + t + 1];
    int m = min(scF, CAPc), n2 = min(tcF, CAPc);
    float bwpart = 0.f;
    for (int idx = tid; idx < 2500; idx += 256) {
        int i = idx / 50, j = idx % 50;
        float d = 0.f;
#pragma unroll
        for (int k = 0; k < 32; ++k) {
            float df = Xs[i * 32 + k] - Xs[j * 32 + k];
            d = fmaf(df, df, d);
        }
        D2[idx] = d;
        bool vi = (i < CAPc) ? (i < m) : (i - CAPc < n2);
        bool vj = (j < CAPc) ? (j < m) : (j - CAPc < n2);
        if (vi && vj) bwpart += d;
    }
    float bwsum = block_reduce256(bwpart, red, tid);
    float ntot = (float)(m + n2);
    float bw = bwsum / fmaxf(ntot * ntot - ntot, 1.f) * 0.25f;  // / KER_MUL^(KER_NUM//2)
    float bws[5];
#pragma unroll
    for (int k = 0; k < 5; ++k) bws[k] = fmaxf(bw * (float)(1 << k), 1e-8f);
    float xx = 0.f, yy = 0.f, xy = 0.f;
    for (int idx = tid; idx < 2500; idx += 256) {
        int i = idx / 50, j = idx % 50;
        bool vi = (i < CAPc) ? (i < m) : (i - CAPc < n2);
        bool vj = (j < CAPc) ? (j < m) : (j - CAPc < n2);
        if (!(vi && vj)) continue;
        float d = D2[idx];
        float kv = 0.f;
#pragma unroll
        for (int k = 0; k < 5; ++k) kv += expf(-d / bws[k]);
        if (i < CAPc && j < CAPc) xx += kv;
        else if (i >= CAPc && j >= CAPc) yy += kv;
        else if (i < CAPc) xy += kv;
    }
    float rxx = block_reduce256(xx, red, tid);
    float ryy = block_reduce256(yy, red, tid);
    float rxy = block_reduce256(xy, red, tid);
    if (tid == 0) {
        float fm = (float)m, fn = (float)n2;
        float XX = rxx / fmaxf(fm * fm, 1.f);
        float YY = ryy / fmaxf(fn * fn, 1.f);
        float XY = rxy / fmaxf(fm * fn, 1.f);
        float loss = XX + YY - 2.f * XY;
        int inc = (scF >= 5 && tcF >= 5) ? 1 : 0;
        losses[t * 2 + 0] = inc ? loss : 0.f;
        losses[t * 2 + 1] = (float)inc;
    }
}

__global__ void final_kernel(const float* __restrict__ losses, float* __restrict__ out) {
    __shared__ float red[128], redc[128];
    int tid = threadIdx.x;
    float s = 0.f, c = 0.f;
    for (int t = tid; t < NTYPE; t += 128) {
        s += losses[t * 2];
        c += losses[t * 2 + 1];
    }
    red[tid] = s;
    redc[tid] = c;
    __syncthreads();
    for (int st = 64; st > 0; st >>= 1) {
        if (tid < st) {
            red[tid] += red[tid + st];
            redc[tid] += redc[tid + st];
        }
        __syncthreads();
    }
    if (tid == 0) out[24832] = redc[0] > 0.f ? red[0] / fmaxf(redc[0], 1.f) : 0.f;
}

extern "C" void kernel_launch(void* const* d_in, const int* in_sizes, int n_in,
                              void* d_out, int out_size, void* d_ws, size_t ws_size,
                              hipStream_t stream) {
    const int* feat = (const int*)d_in[0];
    const int* feat_src = (const int*)d_in[1];
    const int* feat_tar = (const int*)d_in[2];
    const int* ei0 = (const int*)d_in[3];
    const int* ei1 = (const int*)d_in[4];
    const int* ei2 = (const int*)d_in[5];
    const float* mask = (const float*)d_in[7];
    const float* embed = (const float*)d_in[8];
    const float* gcn_w = (const float*)d_in[9];
    const float* gcn_b = (const float*)d_in[10];
    const float* fc_w = (const float*)d_in[11];
    const float* fc_b = (const float*)d_in[12];
    const float* def_w = (const float*)d_in[13];
    const float* def_b = (const float*)d_in[14];
    float* out = (float*)d_out;

    char* wsb = (char*)d_ws;
    float* W = (float*)(wsb + 0);               // 24,000,000
    int* partial = (int*)(wsb + 0);             // 19,200,000 (aliases W; used before W's memset)
    float* T = (float*)(wsb + 24000000);        // 48,000
    float* pool = (float*)(wsb + 24048000);     // 307,200
    float2* pc = (float2*)(wsb + 24355200);     // 1,200,000 (3 x 50000 x 8B)
    float* rs = (float*)(wsb + 25555200);       // 600,000   (3 x 50000 x 4B)
    int* selpos = (int*)(wsb + 26155200);       // 400,000   (src then tar)
    float* h_sel = (float*)(wsb + 26555200);    // 2,380,000 (2 x 119 x 25 x 100 f32)
    int* fullcnt = (int*)(wsb + 28935200);      // 960
    float* X = (float*)(wsb + 28936160);        // 761,600
    float* losses = (float*)(wsb + 29697760);   // 952
    int* chunkcnt = (int*)(wsb + 29698720);     // 188,160
    int* baseb = (int*)(wsb + 29886880);        // 188,160  -> total ~30.1 MB

    const int* eis[3] = {ei0, ei1, ei2};

    hipMemsetAsync(pool, 0, 3 * Gg * DH * sizeof(float), stream);
    hipMemsetAsync(selpos, 0xFF, 2 * Nn * sizeof(int), stream);  // -1

    t_kernel<<<VOC, 128, 0, stream>>>(embed, gcn_w, T);

    selcount_kernel<<<dim3(NCHUNK, 2), 256, 0, stream>>>(feat_src, feat_tar, chunkcnt);
    selprefix_kernel<<<1, 256, 0, stream>>>(chunkcnt, baseb, fullcnt);
    selgather_kernel<<<dim3(NCHUNK, 2), 256, 0, stream>>>(feat_src, feat_tar, baseb,
                                                          selpos, selpos + Nn);

    deghist_kernel<<<dim3(DR * DS, 6), 256, 0, stream>>>(ei0, ei1, ei2, partial);
    degmerge_kernel<<<(6 * DR * DWORDS + 255) / 256, 256, 0, stream>>>(partial, feat, feat_src,
                                                                       feat_tar, mask, pc, rs);

    for (int p = 0; p < 3; ++p) {
        hipMemsetAsync(W, 0, (size_t)Nn * VOC * sizeof(float), stream);
        wacc_kernel<<<(Ee + 255) / 256, 256, 0, stream>>>(eis[p], pc + (size_t)p * Nn, W);
        const int* sp = (p == 0) ? nullptr : (p == 1 ? selpos : selpos + Nn);
        float* hs = h_sel + (size_t)(p == 2 ? NTYPE * CAPc * DH : 0);
        h_kernel<<<(Nn + 63) / 64, 256, 0, stream>>>(W, T, rs + (size_t)p * Nn, sp, hs, gcn_b,
                                                     pool + p * (Gg * DH));
    }

    poolgemm_kernel<<<Gg, 128, 0, stream>>>(pool, fc_w, fc_b, def_w, def_b, out);
    xfeat_kernel<<<NTYPE, 256, 0, stream>>>(h_sel, fullcnt, fc_w, fc_b, X);
    mmd_kernel<<<NTYPE, 256, 0, stream>>>(X, fullcnt, losses);
    final_kernel<<<1, 128, 0, stream>>>(losses, out);
}